// Round 1
// baseline (814.629 us; speedup 1.0000x reference)
//
#include <hip/hip_runtime.h>
#include <math.h>

#define BN    8
#define NN    1024
#define HH    64
#define EE    2
#define ADIM  8
#define STEPS 5
#define K2    2048          // N*E
#define ROWS  (BN*NN)       // 8192

// ---------------- init: h_ws = initial_state; edge_buf = f(initial_state) --------
__global__ __launch_bounds__(256) void init_kernel(
    const float* __restrict__ init_state,
    const float* __restrict__ We, const float* __restrict__ be,
    float* __restrict__ h_ws, float* __restrict__ edge_buf)
{
    __shared__ float h_lds[4][64];
    int t = threadIdx.x;
    int r = t >> 6, hp = t & 63;
    int row = blockIdx.x * 4 + r;              // 0..8191
    float hv = init_state[(size_t)row * 64 + hp];
    h_ws[(size_t)row * 64 + hp] = hv;
    h_lds[r][hp] = hv;
    __syncthreads();
    int b = row >> 10, n = row & 1023;
    #pragma unroll
    for (int e = 0; e < 2; ++e) {
        float acc = be[hp * 2 + e];
        #pragma unroll 8
        for (int c = 0; c < 64; ++c)
            acc += h_lds[r][c] * We[c * 128 + hp * 2 + e];
        edge_buf[(((size_t)(b * 2 + e)) * NN + n) * 64 + hp] = acc;
    }
}

// ---------------- big GEMM: a_part[dir][kc][b][n][h] partials ----------
#define MT  128
#define KT  64
#define KCH 2
#define KPC (K2 / KCH)      // 1024

__global__ __launch_bounds__(256) void big_gemm(
    const float* __restrict__ adj, const float* __restrict__ edge_buf,
    float* __restrict__ a_part)
{
    int bx = blockIdx.x;                 // 256 blocks
    int kc  = bx & 1;
    int dir = (bx >> 1) & 1;
    int mt  = (bx >> 2) & 7;
    int b   = bx >> 5;

    __shared__ float At[KT][MT + 4];     // transposed A: At[kk][r], stride 132
    __shared__ float Bt[KT][HH];         // Bt[kk][c]

    int t  = threadIdx.x;
    int rg = t >> 3;                     // 0..31 -> rows rg*4..rg*4+3
    int cg = t & 7;                      // cols cg*8..cg*8+7

    const float* Ap = adj + ((size_t)(b * NN + mt * MT)) * 4096 + dir * K2 + kc * KPC;
    const float* Bp = edge_buf + (size_t)b * K2 * 64 + (size_t)kc * KPC * 64;

    float acc[4][8];
    #pragma unroll
    for (int i = 0; i < 4; ++i)
        #pragma unroll
        for (int j = 0; j < 8; ++j) acc[i][j] = 0.f;

    for (int k0 = 0; k0 < KPC; k0 += KT) {
        // stage A: 128 rows x 64 k = 2048 float4, 8 per thread (coalesced along k)
        #pragma unroll
        for (int l = 0; l < 8; ++l) {
            int idx = t + l * 256;
            int rr  = idx >> 4;          // 0..127
            int kv  = idx & 15;          // float4 along k
            float4 v = *(const float4*)(Ap + (size_t)rr * 4096 + k0 + kv * 4);
            At[kv * 4 + 0][rr] = v.x;
            At[kv * 4 + 1][rr] = v.y;
            At[kv * 4 + 2][rr] = v.z;
            At[kv * 4 + 3][rr] = v.w;
        }
        // stage B: 64 k x 64 c = 1024 float4, 4 per thread
        #pragma unroll
        for (int l = 0; l < 4; ++l) {
            int idx = t + l * 256;
            int kk  = idx >> 4;
            int c4  = idx & 15;
            *(float4*)&Bt[kk][c4 * 4] = *(const float4*)(Bp + (size_t)(k0 + kk) * 64 + c4 * 4);
        }
        __syncthreads();
        #pragma unroll 4
        for (int kk = 0; kk < KT; ++kk) {
            float4 av  = *(const float4*)&At[kk][rg * 4];
            float4 bv0 = *(const float4*)&Bt[kk][cg * 8];
            float4 bv1 = *(const float4*)&Bt[kk][cg * 8 + 4];
            float bb[8] = {bv0.x, bv0.y, bv0.z, bv0.w, bv1.x, bv1.y, bv1.z, bv1.w};
            #pragma unroll
            for (int j = 0; j < 8; ++j) {
                acc[0][j] += av.x * bb[j];
                acc[1][j] += av.y * bb[j];
                acc[2][j] += av.z * bb[j];
                acc[3][j] += av.w * bb[j];
            }
        }
        __syncthreads();
    }

    float* outp = a_part + (((size_t)dir * KCH + kc) * BN + b) * NN * 64 + (size_t)mt * MT * 64;
    #pragma unroll
    for (int i = 0; i < 4; ++i) {
        float* dst = outp + (size_t)(rg * 4 + i) * 64 + cg * 8;
        *(float4*)dst       = make_float4(acc[i][0], acc[i][1], acc[i][2], acc[i][3]);
        *(float4*)(dst + 4) = make_float4(acc[i][4], acc[i][5], acc[i][6], acc[i][7]);
    }
}

// ---------------- gate + state update + next edge ----------
__global__ __launch_bounds__(256) void gate_kernel(
    const float* __restrict__ a_part,
    const float* __restrict__ Wg, const float* __restrict__ bg,
    const float* __restrict__ We, const float* __restrict__ be,
    float* __restrict__ h_ws, float* __restrict__ edge_buf,
    int compute_edge)
{
    __shared__ float Wg_l[192 * 64];
    __shared__ float a_l[4][192];
    __shared__ float r_l[4][64];
    int t = threadIdx.x;
    #pragma unroll
    for (int l = 0; l < 12; ++l) {
        int idx = t + l * 256;
        *(float4*)&Wg_l[idx * 4] = *(const float4*)&Wg[idx * 4];
    }
    int r = t >> 6, hp = t & 63;
    int row = blockIdx.x * 4 + r;
    int b = row >> 10, n = row & 1023;
    size_t off = (size_t)row * 64 + hp;
    const size_t PART = (size_t)BN * NN * 64;   // 524288

    float a_in  = a_part[off]            + a_part[PART + off];
    float a_out = a_part[2 * PART + off] + a_part[3 * PART + off];
    float h_old = h_ws[off];
    a_l[r][hp]       = a_in;
    a_l[r][64 + hp]  = a_out;
    a_l[r][128 + hp] = h_old;
    __syncthreads();

    float acc12 = 0.f;
    #pragma unroll 8
    for (int k = 0; k < 128; ++k)
        acc12 += a_l[r][k] * Wg_l[k * 64 + hp];

    float zpre = acc12 + bg[hp];
    #pragma unroll 8
    for (int k = 0; k < 64; ++k)
        zpre += a_l[r][128 + k] * Wg_l[(128 + k) * 64 + hp];
    float z = 1.f / (1.f + __expf(-zpre));

    r_l[r][hp] = z * h_old;
    __syncthreads();

    float hpre = acc12 + bg[hp];
    #pragma unroll 8
    for (int k = 0; k < 64; ++k)
        hpre += r_l[r][k] * Wg_l[(128 + k) * 64 + hp];
    float ht = tanhf(hpre);
    float h_new = (1.f - z) * h_old + z * ht;
    h_ws[off] = h_new;
    __syncthreads();                 // all reads of r_l (z*h) done
    r_l[r][hp] = h_new;
    __syncthreads();

    if (compute_edge) {
        #pragma unroll
        for (int e = 0; e < 2; ++e) {
            float acc = be[hp * 2 + e];
            #pragma unroll 8
            for (int c = 0; c < 64; ++c)
                acc += r_l[r][c] * We[c * 128 + hp * 2 + e];
            edge_buf[(((size_t)(b * 2 + e)) * NN + n) * 64 + hp] = acc;
        }
    }
}

// ---------------- output head ----------
__global__ __launch_bounds__(256) void head_kernel(
    const float* __restrict__ h_ws, const float* __restrict__ ann,
    const float* __restrict__ Wh, const float* __restrict__ bh,
    const float* __restrict__ Wo, const float* __restrict__ bo,
    float* __restrict__ out)
{
    __shared__ float Wh_l[72 * 64];
    __shared__ float ha[4][72];
    int t = threadIdx.x;
    #pragma unroll
    for (int l = 0; l < 18; ++l) {
        int idx = t + l * 256;       // 4608 floats
        Wh_l[idx] = Wh[idx];
    }
    int r = t >> 6, hp = t & 63;
    int row = blockIdx.x * 4 + r;
    ha[r][hp] = h_ws[(size_t)row * 64 + hp];
    if (hp < ADIM) ha[r][64 + hp] = ann[(size_t)row * ADIM + hp];
    __syncthreads();

    float acc = bh[hp];
    #pragma unroll 8
    for (int k = 0; k < 72; ++k)
        acc += ha[r][k] * Wh_l[k * 64 + hp];
    float v = tanhf(acc) * Wo[hp];
    #pragma unroll
    for (int o = 32; o; o >>= 1) v += __shfl_down(v, o, 64);
    if (hp == 0) out[row] = v + bo[0];
}

extern "C" void kernel_launch(void* const* d_in, const int* in_sizes, int n_in,
                              void* d_out, int out_size, void* d_ws, size_t ws_size,
                              hipStream_t stream) {
    const float* init_state = (const float*)d_in[0];
    const float* ann = (const float*)d_in[1];
    const float* adj = (const float*)d_in[2];
    const float* We  = (const float*)d_in[3];
    const float* be  = (const float*)d_in[4];
    const float* Wg  = (const float*)d_in[5];
    const float* bg  = (const float*)d_in[6];
    const float* Wh  = (const float*)d_in[7];
    const float* bh  = (const float*)d_in[8];
    const float* Wo  = (const float*)d_in[9];
    const float* bo  = (const float*)d_in[10];
    float* out = (float*)d_out;

    float* h_ws   = (float*)d_ws;                 // 524288 f
    float* edge_b = h_ws + (size_t)ROWS * 64;     // 1048576 f
    float* a_part = edge_b + (size_t)BN * K2 * 64; // 4 * 524288 f  (~14.7 MB total)

    init_kernel<<<dim3(ROWS / 4), dim3(256), 0, stream>>>(init_state, We, be, h_ws, edge_b);
    for (int s = 0; s < STEPS; ++s) {
        big_gemm<<<dim3(256), dim3(256), 0, stream>>>(adj, edge_b, a_part);
        gate_kernel<<<dim3(ROWS / 4), dim3(256), 0, stream>>>(
            a_part, Wg, bg, We, be, h_ws, edge_b, (s < STEPS - 1) ? 1 : 0);
    }
    head_kernel<<<dim3(ROWS / 4), dim3(256), 0, stream>>>(h_ws, ann, Wh, bh, Wo, bo, out);
}

// Round 2
// 530.812 us; speedup vs baseline: 1.5347x; 1.5347x over previous
//
#include <hip/hip_runtime.h>
#include <math.h>

#define BN    8
#define NN    1024
#define HH    64
#define EE    2
#define ADIM  8
#define STEPS 5
#define K2    2048          // N*E
#define ROWS  (BN*NN)       // 8192
#define KCH   4             // split-K chunks per direction
#define KPC   (K2/KCH)      // 512
#define PART  ((size_t)ROWS*64)   // 524288 floats per partial segment

typedef __attribute__((ext_vector_type(8))) short bf16x8;
typedef __attribute__((ext_vector_type(4))) float f32x4;

__device__ __forceinline__ unsigned short f2bf(float f) {
    unsigned int u = __float_as_uint(f);
    u += 0x7FFF + ((u >> 16) & 1);          // round-to-nearest-even
    return (unsigned short)(u >> 16);
}

// ---------------- one-time: adjacency fp32 -> bf16 ----------------
// 33554432 elems = 8388608 float4 tasks; 8192 blocks x 256 thr x 4 tasks
__global__ __launch_bounds__(256) void conv_adj(
    const float* __restrict__ in, unsigned short* __restrict__ out)
{
    int tid = blockIdx.x * 256 + threadIdx.x;     // 0..2097151
    #pragma unroll
    for (int i = 0; i < 4; ++i) {
        size_t idx = (size_t)tid + (size_t)i * 2097152;
        float4 v = ((const float4*)in)[idx];
        ushort4 o;
        o.x = f2bf(v.x); o.y = f2bf(v.y); o.z = f2bf(v.z); o.w = f2bf(v.w);
        ((ushort4*)out)[idx] = o;
    }
}

// ---------------- init: h_ws = initial_state; edge_t = f(initial_state) ----------
__global__ __launch_bounds__(256) void init_kernel(
    const float* __restrict__ init_state,
    const float* __restrict__ We, const float* __restrict__ be,
    float* __restrict__ h_ws, unsigned short* __restrict__ edge_t)
{
    __shared__ float h_lds[4][64];
    int t = threadIdx.x;
    int r = t >> 6, hp = t & 63;
    int row = blockIdx.x * 4 + r;              // 0..8191
    float hv = init_state[(size_t)row * 64 + hp];
    h_ws[(size_t)row * 64 + hp] = hv;
    h_lds[r][hp] = hv;
    __syncthreads();
    int b = row >> 10, n = row & 1023;
    #pragma unroll
    for (int e = 0; e < 2; ++e) {
        float acc = be[hp * 2 + e];
        #pragma unroll 8
        for (int c = 0; c < 64; ++c)
            acc += h_lds[r][c] * We[c * 128 + hp * 2 + e];
        // edge_t[b][h][k = e*1024 + n]
        edge_t[((size_t)b * 64 + hp) * K2 + e * NN + n] = f2bf(acc);
    }
}

// ---------------- big GEMM (bf16 MFMA): a_part[dir*KCH+kc][b][n][h] ----------
// grid = 1024 blocks: kc(4) x dir(2) x mt(16) x b(8); MT=64, KT=64
__global__ __launch_bounds__(256) void big_gemm(
    const unsigned short* __restrict__ adjb,     // [b][n][4096] bf16
    const unsigned short* __restrict__ edge_t,   // [b][64][2048] bf16
    float* __restrict__ a_part)
{
    int bx = blockIdx.x;
    int kc  = bx & 3;
    int dir = (bx >> 2) & 1;
    int mt  = (bx >> 3) & 15;
    int b   = bx >> 7;

    __shared__ unsigned short As[64][72];   // [row][k], pad 8 -> 2-way max
    __shared__ unsigned short Bs[64][72];   // [col(h)][k]

    int t    = threadIdx.x;
    int w    = t >> 6;           // wave 0..3 -> rows w*16..w*16+15
    int lane = t & 63;
    int l15  = lane & 15;
    int q    = lane >> 4;

    const unsigned short* Ap = adjb + ((size_t)(b * NN + mt * 64)) * 4096
                                    + dir * K2 + kc * KPC;
    const unsigned short* Bp = edge_t + (size_t)b * 64 * K2 + kc * KPC;

    f32x4 acc[4];
    #pragma unroll
    for (int ct = 0; ct < 4; ++ct) acc[ct] = (f32x4){0.f, 0.f, 0.f, 0.f};

    for (int k0 = 0; k0 < KPC; k0 += 64) {
        // stage A: 64 rows x 64 k bf16 = 512 x 16B; 2 per thread
        #pragma unroll
        for (int l = 0; l < 2; ++l) {
            int idx = t + l * 256;
            int rr  = idx >> 3;
            int ck  = idx & 7;
            uint4 v = *(const uint4*)(Ap + (size_t)rr * 4096 + k0 + ck * 8);
            *(uint4*)&As[rr][ck * 8] = v;
        }
        // stage B: 64 h-rows x 64 k bf16, straight copy (edge_t already [h][k])
        #pragma unroll
        for (int l = 0; l < 2; ++l) {
            int idx = t + l * 256;
            int rr  = idx >> 3;
            int ck  = idx & 7;
            uint4 v = *(const uint4*)(Bp + (size_t)rr * K2 + k0 + ck * 8);
            *(uint4*)&Bs[rr][ck * 8] = v;
        }
        __syncthreads();
        #pragma unroll
        for (int kk = 0; kk < 64; kk += 32) {
            bf16x8 af = *(const bf16x8*)&As[w * 16 + l15][kk + q * 8];
            #pragma unroll
            for (int ct = 0; ct < 4; ++ct) {
                bf16x8 bfr = *(const bf16x8*)&Bs[ct * 16 + l15][kk + q * 8];
                acc[ct] = __builtin_amdgcn_mfma_f32_16x16x32_bf16(af, bfr, acc[ct], 0, 0, 0);
            }
        }
        __syncthreads();
    }

    // C/D layout: col = lane&15, row = (lane>>4)*4 + reg
    float* outp = a_part + (size_t)(dir * KCH + kc) * PART
                + ((size_t)(b * NN + mt * 64)) * 64;
    #pragma unroll
    for (int ct = 0; ct < 4; ++ct)
        #pragma unroll
        for (int i = 0; i < 4; ++i) {
            int row = w * 16 + q * 4 + i;
            outp[(size_t)row * 64 + ct * 16 + l15] = acc[ct][i];
        }
}

// ---------------- gate + state update + next edge (16 rows/block) ----------
__global__ __launch_bounds__(256) void gate_kernel(
    const float* __restrict__ a_part,
    const float* __restrict__ Wg, const float* __restrict__ bg,
    const float* __restrict__ We, const float* __restrict__ be,
    float* __restrict__ h_ws, unsigned short* __restrict__ edge_t,
    int compute_edge)
{
    __shared__ float Wg_l[192 * 64];
    __shared__ float a_l[4][192];
    __shared__ float r_l[4][64];
    int t = threadIdx.x;
    #pragma unroll
    for (int l = 0; l < 12; ++l) {
        int idx = t + l * 256;
        *(float4*)&Wg_l[idx * 4] = *(const float4*)&Wg[idx * 4];
    }
    int r = t >> 6, hp = t & 63;

    for (int rr = 0; rr < 4; ++rr) {
        int row = blockIdx.x * 16 + rr * 4 + r;
        int b = row >> 10, n = row & 1023;
        size_t off = (size_t)row * 64 + hp;

        float a_in = 0.f, a_out = 0.f;
        #pragma unroll
        for (int kcc = 0; kcc < KCH; ++kcc) {
            a_in  += a_part[(size_t)kcc * PART + off];
            a_out += a_part[(size_t)(KCH + kcc) * PART + off];
        }
        float h_old = h_ws[off];
        a_l[r][hp]       = a_in;
        a_l[r][64 + hp]  = a_out;
        a_l[r][128 + hp] = h_old;
        __syncthreads();

        float acc12 = 0.f;
        #pragma unroll 8
        for (int k = 0; k < 128; ++k)
            acc12 += a_l[r][k] * Wg_l[k * 64 + hp];

        float zpre = acc12 + bg[hp];
        #pragma unroll 8
        for (int k = 0; k < 64; ++k)
            zpre += a_l[r][128 + k] * Wg_l[(128 + k) * 64 + hp];
        float z = 1.f / (1.f + __expf(-zpre));

        r_l[r][hp] = z * h_old;
        __syncthreads();

        float hpre = acc12 + bg[hp];
        #pragma unroll 8
        for (int k = 0; k < 64; ++k)
            hpre += r_l[r][k] * Wg_l[(128 + k) * 64 + hp];
        float ht = tanhf(hpre);
        float h_new = (1.f - z) * h_old + z * ht;
        h_ws[off] = h_new;
        __syncthreads();
        r_l[r][hp] = h_new;
        __syncthreads();

        if (compute_edge) {
            #pragma unroll
            for (int e = 0; e < 2; ++e) {
                float acc = be[hp * 2 + e];
                #pragma unroll 8
                for (int c = 0; c < 64; ++c)
                    acc += r_l[r][c] * We[c * 128 + hp * 2 + e];
                edge_t[((size_t)b * 64 + hp) * K2 + e * NN + n] = f2bf(acc);
            }
        }
        __syncthreads();
    }
}

// ---------------- output head ----------
__global__ __launch_bounds__(256) void head_kernel(
    const float* __restrict__ h_ws, const float* __restrict__ ann,
    const float* __restrict__ Wh, const float* __restrict__ bh,
    const float* __restrict__ Wo, const float* __restrict__ bo,
    float* __restrict__ out)
{
    __shared__ float Wh_l[72 * 64];
    __shared__ float ha[4][72];
    int t = threadIdx.x;
    #pragma unroll
    for (int l = 0; l < 18; ++l) {
        int idx = t + l * 256;       // 4608 floats
        Wh_l[idx] = Wh[idx];
    }
    int r = t >> 6, hp = t & 63;
    int row = blockIdx.x * 4 + r;
    ha[r][hp] = h_ws[(size_t)row * 64 + hp];
    if (hp < ADIM) ha[r][64 + hp] = ann[(size_t)row * ADIM + hp];
    __syncthreads();

    float acc = bh[hp];
    #pragma unroll 8
    for (int k = 0; k < 72; ++k)
        acc += ha[r][k] * Wh_l[k * 64 + hp];
    float v = tanhf(acc) * Wo[hp];
    #pragma unroll
    for (int o = 32; o; o >>= 1) v += __shfl_down(v, o, 64);
    if (hp == 0) out[row] = v + bo[0];
}

extern "C" void kernel_launch(void* const* d_in, const int* in_sizes, int n_in,
                              void* d_out, int out_size, void* d_ws, size_t ws_size,
                              hipStream_t stream) {
    const float* init_state = (const float*)d_in[0];
    const float* ann = (const float*)d_in[1];
    const float* adj = (const float*)d_in[2];
    const float* We  = (const float*)d_in[3];
    const float* be  = (const float*)d_in[4];
    const float* Wg  = (const float*)d_in[5];
    const float* bg  = (const float*)d_in[6];
    const float* Wh  = (const float*)d_in[7];
    const float* bh  = (const float*)d_in[8];
    const float* Wo  = (const float*)d_in[9];
    const float* bo  = (const float*)d_in[10];
    float* out = (float*)d_out;

    // workspace layout (bytes):
    //   adj_bf  : 33554432 ushort = 67108864 B
    //   edge_t  :  1048576 ushort =  2097152 B
    //   h_ws    :   524288 float  =  2097152 B
    //   a_part  :  4194304 float  = 16777216 B   (8 segments)
    char* wsb = (char*)d_ws;
    unsigned short* adj_bf = (unsigned short*)wsb;
    unsigned short* edge_t = (unsigned short*)(wsb + 67108864);
    float* h_ws   = (float*)(wsb + 67108864 + 2097152);
    float* a_part = (float*)(wsb + 67108864 + 2097152 + 2097152);

    conv_adj<<<dim3(8192), dim3(256), 0, stream>>>(adj, adj_bf);
    init_kernel<<<dim3(ROWS / 4), dim3(256), 0, stream>>>(init_state, We, be, h_ws, edge_t);
    for (int s = 0; s < STEPS; ++s) {
        big_gemm<<<dim3(1024), dim3(256), 0, stream>>>(adj_bf, edge_t, a_part);
        gate_kernel<<<dim3(ROWS / 16), dim3(256), 0, stream>>>(
            a_part, Wg, bg, We, be, h_ws, edge_t, (s < STEPS - 1) ? 1 : 0);
    }
    head_kernel<<<dim3(ROWS / 4), dim3(256), 0, stream>>>(h_ws, ann, Wh, bh, Wo, bo, out);
}

// Round 3
// 499.375 us; speedup vs baseline: 1.6313x; 1.0630x over previous
//
#include <hip/hip_runtime.h>
#include <math.h>

#define BN    8
#define NN    1024
#define HH    64
#define ADIM  8
#define STEPS 5
#define K2    2048                 // N*E
#define ROWS  (BN*NN)              // 8192
#define KCH   8                    // split-K chunks per direction
#define KPC   (K2/KCH)             // 256
#define PART  ((size_t)ROWS*64)    // 524288 floats per partial segment

typedef __attribute__((ext_vector_type(8))) short bf16x8;
typedef __attribute__((ext_vector_type(4))) float f32x4;

__device__ __forceinline__ unsigned short f2bf(float f) {
    unsigned int u = __float_as_uint(f);
    u += 0x7FFF + ((u >> 16) & 1);          // round-to-nearest-even
    return (unsigned short)(u >> 16);
}

// ---------------- one-time: adjacency fp32 -> bf16 ----------------
__global__ __launch_bounds__(256) void conv_adj(
    const float* __restrict__ in, unsigned short* __restrict__ out)
{
    int tid = blockIdx.x * 256 + threadIdx.x;     // 0..2097151
    #pragma unroll
    for (int i = 0; i < 4; ++i) {
        size_t idx = (size_t)tid + (size_t)i * 2097152;
        float4 v = ((const float4*)in)[idx];
        ushort4 o;
        o.x = f2bf(v.x); o.y = f2bf(v.y); o.z = f2bf(v.z); o.w = f2bf(v.w);
        ((ushort4*)out)[idx] = o;
    }
}

// ---------------- init: h_ws = initial_state; edge_t = f(initial_state) ----------
__global__ __launch_bounds__(256) void init_kernel(
    const float* __restrict__ init_state,
    const float* __restrict__ We, const float* __restrict__ be,
    float* __restrict__ h_ws, unsigned short* __restrict__ edge_t)
{
    __shared__ float h_lds[4][65];
    int t = threadIdx.x;
    int r = t >> 6, hp = t & 63;
    int row = blockIdx.x * 4 + r;
    float hv = init_state[(size_t)row * 64 + hp];
    h_ws[(size_t)row * 64 + hp] = hv;
    h_lds[r][hp] = hv;
    __syncthreads();
    int b = row >> 10, n = row & 1023;
    #pragma unroll
    for (int e = 0; e < 2; ++e) {
        float acc = be[hp * 2 + e];
        #pragma unroll 8
        for (int c = 0; c < 64; ++c)
            acc += h_lds[r][c] * We[c * 128 + hp * 2 + e];
        edge_t[((size_t)b * 64 + hp) * K2 + e * NN + n] = f2bf(acc);
    }
}

// ---------------- big GEMM (bf16 MFMA), barrier-free K-loop ----------
// grid = 2048: kc(8) x dir(2) x mt(16) x b(8); 64 rows/block, 4 waves x 16 rows
__global__ __launch_bounds__(256) void big_gemm(
    const unsigned short* __restrict__ adjb,     // [b][n][4096] bf16
    const unsigned short* __restrict__ edge_t,   // [b][64][2048] bf16
    float* __restrict__ a_part)
{
    int bx = blockIdx.x;
    int kc  = bx & 7;
    int dir = (bx >> 3) & 1;
    int mt  = (bx >> 4) & 15;
    int b   = bx >> 8;

    __shared__ unsigned short Bs[64][264];   // [h][k], stride 264 (odd multiple of 8)

    int t = threadIdx.x;
    // stage B once: 64 h-rows x 256 k, straight copy from [b][h][2048]
    {
        int h = t >> 2, part = t & 3;
        const unsigned short* src = edge_t + ((size_t)b * 64 + h) * K2 + kc * KPC + part * 64;
        #pragma unroll
        for (int i = 0; i < 8; ++i)
            *(uint4*)&Bs[h][part * 64 + i * 8] = *(const uint4*)(src + i * 8);
    }
    __syncthreads();

    int w = t >> 6, lane = t & 63, l15 = lane & 15, q = lane >> 4;
    const unsigned short* Ap = adjb
        + ((size_t)(b * NN + mt * 64 + w * 16 + l15)) * 4096
        + dir * K2 + kc * KPC + q * 8;

    f32x4 acc[4];
    #pragma unroll
    for (int ct = 0; ct < 4; ++ct) acc[ct] = (f32x4){0.f, 0.f, 0.f, 0.f};

    #pragma unroll
    for (int ks = 0; ks < 8; ++ks) {
        bf16x8 af = *(const bf16x8*)(Ap + ks * 32);
        #pragma unroll
        for (int ct = 0; ct < 4; ++ct) {
            bf16x8 bfr = *(const bf16x8*)&Bs[ct * 16 + l15][ks * 32 + q * 8];
            acc[ct] = __builtin_amdgcn_mfma_f32_16x16x32_bf16(af, bfr, acc[ct], 0, 0, 0);
        }
    }

    // C/D layout: col = lane&15, row = (lane>>4)*4 + reg
    float* outp = a_part + (size_t)(dir * KCH + kc) * PART
                + ((size_t)(b * NN + mt * 64)) * 64;
    #pragma unroll
    for (int ct = 0; ct < 4; ++ct)
        #pragma unroll
        for (int i = 0; i < 4; ++i) {
            int rloc = w * 16 + q * 4 + i;
            outp[(size_t)rloc * 64 + ct * 16 + l15] = acc[ct][i];
        }
}

// ---------------- gate + state update; thread = (row, j-quad); 1 barrier ----------
__global__ __launch_bounds__(256) void gate_kernel(
    const float* __restrict__ a_part,
    const float* __restrict__ Wg, const float* __restrict__ bg,
    float* __restrict__ h_ws)
{
    __shared__ float Wg_l[12288];        // 48 KB
    __shared__ float a_l[16][193];       // 12.35 KB; stride 193 -> conflict-free bcast
    int t = threadIdx.x;
    #pragma unroll
    for (int l = 0; l < 12; ++l) {
        int idx = t + l * 256;
        *(float4*)&Wg_l[idx * 4] = *(const float4*)&Wg[idx * 4];
    }
    int rloc = t >> 4, jq = t & 15;
    int row = blockIdx.x * 16 + rloc;
    size_t off = (size_t)row * 64 + jq * 4;

    float4 ain = make_float4(0.f, 0.f, 0.f, 0.f);
    float4 aou = make_float4(0.f, 0.f, 0.f, 0.f);
    #pragma unroll
    for (int kcc = 0; kcc < KCH; ++kcc) {
        float4 p = *(const float4*)(a_part + (size_t)kcc * PART + off);
        ain.x += p.x; ain.y += p.y; ain.z += p.z; ain.w += p.w;
        float4 qv = *(const float4*)(a_part + (size_t)(KCH + kcc) * PART + off);
        aou.x += qv.x; aou.y += qv.y; aou.z += qv.z; aou.w += qv.w;
    }
    float4 hold = *(const float4*)(h_ws + off);

    a_l[rloc][jq * 4 + 0] = ain.x; a_l[rloc][jq * 4 + 1] = ain.y;
    a_l[rloc][jq * 4 + 2] = ain.z; a_l[rloc][jq * 4 + 3] = ain.w;
    a_l[rloc][64 + jq * 4 + 0] = aou.x; a_l[rloc][64 + jq * 4 + 1] = aou.y;
    a_l[rloc][64 + jq * 4 + 2] = aou.z; a_l[rloc][64 + jq * 4 + 3] = aou.w;
    a_l[rloc][128 + jq * 4 + 0] = hold.x; a_l[rloc][128 + jq * 4 + 1] = hold.y;
    a_l[rloc][128 + jq * 4 + 2] = hold.z; a_l[rloc][128 + jq * 4 + 3] = hold.w;
    __syncthreads();

    float acc[4] = {0.f, 0.f, 0.f, 0.f};       // shared k<128 part
    #pragma unroll 8
    for (int k = 0; k < 128; ++k) {
        float av = a_l[rloc][k];
        float4 wg = *(const float4*)&Wg_l[k * 64 + jq * 4];
        acc[0] += av * wg.x; acc[1] += av * wg.y;
        acc[2] += av * wg.z; acc[3] += av * wg.w;
    }
    float zp[4] = {acc[0], acc[1], acc[2], acc[3]};
    #pragma unroll 8
    for (int k = 0; k < 64; ++k) {
        float hv = a_l[rloc][128 + k];
        float4 wg = *(const float4*)&Wg_l[(128 + k) * 64 + jq * 4];
        zp[0] += hv * wg.x; zp[1] += hv * wg.y;
        zp[2] += hv * wg.z; zp[3] += hv * wg.w;
    }
    float4 bgv = *(const float4*)(bg + jq * 4);
    float hv4[4] = {hold.x, hold.y, hold.z, hold.w};
    float bg4[4] = {bgv.x, bgv.y, bgv.z, bgv.w};
    float z[4], zh[4];
    #pragma unroll
    for (int i = 0; i < 4; ++i) {
        z[i]  = 1.f / (1.f + __expf(-(zp[i] + bg4[i])));
        zh[i] = z[i] * hv4[i];
    }
    // h-tilde: needs zh_k for all k of the row; rows are 16-lane groups -> shuffle
    int lane = t & 63;
    int gbase = lane & 48;
    #pragma unroll
    for (int k = 0; k < 64; ++k) {
        float zhk = __shfl(zh[k & 3], gbase | (k >> 2), 64);
        float4 wg = *(const float4*)&Wg_l[(128 + k) * 64 + jq * 4];
        acc[0] += zhk * wg.x; acc[1] += zhk * wg.y;
        acc[2] += zhk * wg.z; acc[3] += zhk * wg.w;
    }
    float hn[4];
    #pragma unroll
    for (int i = 0; i < 4; ++i) {
        float ht = tanhf(acc[i] + bg4[i]);
        hn[i] = (1.f - z[i]) * hv4[i] + z[i] * ht;
    }
    *(float4*)(h_ws + off) = make_float4(hn[0], hn[1], hn[2], hn[3]);
}

// ---------------- edge projection: edge_t = f(h), transposed store ----------
__global__ __launch_bounds__(256) void edge_kernel(
    const float* __restrict__ h_ws,
    const float* __restrict__ We, const float* __restrict__ be,
    unsigned short* __restrict__ edge_t)
{
    __shared__ float We_l[8192];         // 32 KB
    __shared__ float h_lds[16][65];
    int t = threadIdx.x;
    #pragma unroll
    for (int l = 0; l < 8; ++l) {
        int idx = t + l * 256;
        *(float4*)&We_l[idx * 4] = *(const float4*)&We[idx * 4];
    }
    int rloc = t >> 4, tq = t & 15;
    int row = blockIdx.x * 16 + rloc;
    float4 h4 = *(const float4*)(h_ws + (size_t)row * 64 + tq * 4);
    h_lds[rloc][tq * 4 + 0] = h4.x; h_lds[rloc][tq * 4 + 1] = h4.y;
    h_lds[rloc][tq * 4 + 2] = h4.z; h_lds[rloc][tq * 4 + 3] = h4.w;
    __syncthreads();

    float acc[8];
    #pragma unroll
    for (int m = 0; m < 8; ++m) acc[m] = be[tq * 8 + m];
    #pragma unroll 4
    for (int c = 0; c < 64; ++c) {
        float hv = h_lds[rloc][c];
        float4 w0 = *(const float4*)&We_l[c * 128 + tq * 8];
        float4 w1 = *(const float4*)&We_l[c * 128 + tq * 8 + 4];
        acc[0] += hv * w0.x; acc[1] += hv * w0.y; acc[2] += hv * w0.z; acc[3] += hv * w0.w;
        acc[4] += hv * w1.x; acc[5] += hv * w1.y; acc[6] += hv * w1.z; acc[7] += hv * w1.w;
    }
    int b = row >> 10, n = row & 1023;
    #pragma unroll
    for (int m = 0; m < 8; ++m) {
        int o = tq * 8 + m;
        int hp = o >> 1, e = o & 1;
        edge_t[((size_t)b * 64 + hp) * K2 + e * NN + n] = f2bf(acc[m]);
    }
}

// ---------------- output head ----------
__global__ __launch_bounds__(256) void head_kernel(
    const float* __restrict__ h_ws, const float* __restrict__ ann,
    const float* __restrict__ Wh, const float* __restrict__ bh,
    const float* __restrict__ Wo, const float* __restrict__ bo,
    float* __restrict__ out)
{
    __shared__ float Wh_l[72 * 64];
    __shared__ float ha[4][72];
    int t = threadIdx.x;
    #pragma unroll
    for (int l = 0; l < 18; ++l) {
        int idx = t + l * 256;
        Wh_l[idx] = Wh[idx];
    }
    int r = t >> 6, hp = t & 63;
    int row = blockIdx.x * 4 + r;
    ha[r][hp] = h_ws[(size_t)row * 64 + hp];
    if (hp < ADIM) ha[r][64 + hp] = ann[(size_t)row * ADIM + hp];
    __syncthreads();

    float acc = bh[hp];
    #pragma unroll 8
    for (int k = 0; k < 72; ++k)
        acc += ha[r][k] * Wh_l[k * 64 + hp];
    float v = tanhf(acc) * Wo[hp];
    #pragma unroll
    for (int o = 32; o; o >>= 1) v += __shfl_down(v, o, 64);
    if (hp == 0) out[row] = v + bo[0];
}

extern "C" void kernel_launch(void* const* d_in, const int* in_sizes, int n_in,
                              void* d_out, int out_size, void* d_ws, size_t ws_size,
                              hipStream_t stream) {
    const float* init_state = (const float*)d_in[0];
    const float* ann = (const float*)d_in[1];
    const float* adj = (const float*)d_in[2];
    const float* We  = (const float*)d_in[3];
    const float* be  = (const float*)d_in[4];
    const float* Wg  = (const float*)d_in[5];
    const float* bg  = (const float*)d_in[6];
    const float* Wh  = (const float*)d_in[7];
    const float* bh  = (const float*)d_in[8];
    const float* Wo  = (const float*)d_in[9];
    const float* bo  = (const float*)d_in[10];
    float* out = (float*)d_out;

    // ws: adj_bf 64 MB | edge_t 2 MB | h_ws 2 MB | a_part 32 MB (16 segs)
    char* wsb = (char*)d_ws;
    unsigned short* adj_bf = (unsigned short*)wsb;
    unsigned short* edge_t = (unsigned short*)(wsb + 67108864);
    float* h_ws   = (float*)(wsb + 67108864 + 2097152);
    float* a_part = (float*)(wsb + 67108864 + 2097152 + 2097152);

    conv_adj<<<dim3(8192), dim3(256), 0, stream>>>(adj, adj_bf);
    init_kernel<<<dim3(ROWS / 4), dim3(256), 0, stream>>>(init_state, We, be, h_ws, edge_t);
    for (int s = 0; s < STEPS; ++s) {
        big_gemm<<<dim3(2048), dim3(256), 0, stream>>>(adj_bf, edge_t, a_part);
        gate_kernel<<<dim3(ROWS / 16), dim3(256), 0, stream>>>(a_part, Wg, bg, h_ws);
        if (s < STEPS - 1)
            edge_kernel<<<dim3(ROWS / 16), dim3(256), 0, stream>>>(h_ws, We, be, edge_t);
    }
    head_kernel<<<dim3(ROWS / 4), dim3(256), 0, stream>>>(h_ws, ann, Wh, bh, Wo, bo, out);
}